// Round 5
// baseline (5467.901 us; speedup 1.0000x reference)
//
#include <hip/hip_runtime.h>
#include <stdint.h>

// Forbid mul+add contraction file-wide: pk_fma would change rounding vs the
// reference's separate mul/add. All critical scalar math uses __f*_rn anyway.
#pragma clang fp contract(off)

typedef unsigned long long u64;
typedef unsigned int u32;
typedef float v2f __attribute__((ext_vector_type(2)));

#define BB 8
#define NN 4096
#define SS 1024
#define EE 102      // int(0.1 * 1024)
#define NBB 3072    // N - S
#define FT 256      // fps threads (4 waves)
#define PT 16       // points per thread (contiguous: thread t owns [16t,16t+16))
#define NP 8        // point-pairs per thread
#define SEL_T 512

// DPP wave64 max-reduce step (bound_ctrl: OOB lanes read 0; values >= 0).
template <int CTRL>
__device__ __forceinline__ float maxdpp(float v) {
  int m = __builtin_amdgcn_update_dpp(0, __float_as_int(v), CTRL, 0xf, 0xf, true);
  return fmaxf(v, __int_as_float(m));
}

// ---------------- FPS kernel: one block per batch ----------------
// Exact replica of _fps_order: d = (dx*dx+dy*dy)+dz*dz (no FMA), mind=min,
// argmax with lowest-index-first ties. Packed-f32 (v_pk_*) for the distance
// math: per-half rounding == scalar rn, so bitwise identical.
__global__ __launch_bounds__(FT) void fps_kernel(const float* __restrict__ x,
                                                 int* __restrict__ idxs) {
  const int b = blockIdx.x;
  const int t = threadIdx.x;
  const int w = t >> 6;
  const int lane = t & 63;
  const float* xb = x + (size_t)b * NN * 3;

  __shared__ u64 rkey[2][4];      // per-wave candidate key, double-buffered
  __shared__ float4 rcoord[2][4]; // per-wave candidate coords

  v2f px[NP], py[NP], pz[NP], mind[NP];

  // 16 contiguous points = 12 float4 per thread (coalesced)
  const float4* xb4 = (const float4*)xb;
  float4 f[12];
#pragma unroll
  for (int j = 0; j < 12; ++j) f[j] = xb4[t * 12 + j];
#pragma unroll
  for (int g = 0; g < 4; ++g) {
    float4 a = f[g * 3 + 0], c = f[g * 3 + 1], d = f[g * 3 + 2];
    // points 4g..4g+3: (a.x,a.y,a.z)(a.w,c.x,c.y)(c.z,c.w,d.x)(d.y,d.z,d.w)
    px[g * 2 + 0].x = a.x; py[g * 2 + 0].x = a.y; pz[g * 2 + 0].x = a.z;
    px[g * 2 + 0].y = a.w; py[g * 2 + 0].y = c.x; pz[g * 2 + 0].y = c.y;
    px[g * 2 + 1].x = c.z; py[g * 2 + 1].x = c.w; pz[g * 2 + 1].x = d.x;
    px[g * 2 + 1].y = d.y; py[g * 2 + 1].y = d.z; pz[g * 2 + 1].y = d.w;
  }
#pragma unroll
  for (int q = 0; q < NP; ++q) { mind[q].x = __builtin_inff(); mind[q].y = __builtin_inff(); }

  if (t == 0) {
    idxs[(size_t)b * NN] = 0;
    // initial lp broadcast via buf-1 slot (first overwritten at it=1, which is
    // after barrier(it=0) -> no race with these init reads)
    rcoord[1][0] = make_float4(px[0].x, py[0].x, pz[0].x, 0.0f);
  }
  __syncthreads();
  float4 lp0 = rcoord[1][0];
  float lx = lp0.x, ly = lp0.y, lz = lp0.z;

  for (int it = 0; it < NN - 1; ++it) {
    const int buf = it & 1;
    v2f lx2, ly2, lz2;
    lx2.x = lx; lx2.y = lx; ly2.x = ly; ly2.y = ly; lz2.x = lz; lz2.y = lz;

    float bestv = -1.0f;
    int bq = 0;
#pragma unroll
    for (int q = 0; q < NP; ++q) {
      v2f dx = px[q] - lx2;                    // v_pk_add (neg) : rn per half
      v2f dy = py[q] - ly2;
      v2f dz = pz[q] - lz2;
      v2f dd = (dx * dx + dy * dy) + dz * dz;  // pk_mul/pk_add, no contraction
      float m0 = fminf(mind[q].x, dd.x);
      float m1 = fminf(mind[q].y, dd.y);
      mind[q].x = m0; mind[q].y = m1;
      // ascending global index order; strict '>' keeps the lowest index
      if (m0 > bestv) { bestv = m0; bq = 2 * q; }
      if (m1 > bestv) { bestv = m1; bq = 2 * q + 1; }
    }

    // wave64 max via DPP (VALU only), result in lane 63
    float r = bestv;
    r = maxdpp<0x111>(r);   // row_shr:1
    r = maxdpp<0x112>(r);   // row_shr:2
    r = maxdpp<0x114>(r);   // row_shr:4
    r = maxdpp<0x118>(r);   // row_shr:8
    r = maxdpp<0x142>(r);   // row_bcast:15
    r = maxdpp<0x143>(r);   // row_bcast:31
    int wmaxb = __builtin_amdgcn_readlane(__float_as_int(r), 63);

    // static cndmask tree: this lane's best-point coords (fills DPP stalls)
    const bool s0 = (bq & 1) != 0, s1 = (bq & 2) != 0,
               s2 = (bq & 4) != 0, s3 = (bq & 8) != 0;
    float e0x[8], e0y[8], e0z[8];
#pragma unroll
    for (int j = 0; j < 8; ++j) {
      e0x[j] = s0 ? px[j].y : px[j].x;
      e0y[j] = s0 ? py[j].y : py[j].x;
      e0z[j] = s0 ? pz[j].y : pz[j].x;
    }
    float e1x[4], e1y[4], e1z[4];
#pragma unroll
    for (int j = 0; j < 4; ++j) {
      e1x[j] = s1 ? e0x[2 * j + 1] : e0x[2 * j];
      e1y[j] = s1 ? e0y[2 * j + 1] : e0y[2 * j];
      e1z[j] = s1 ? e0z[2 * j + 1] : e0z[2 * j];
    }
    float e2x[2], e2y[2], e2z[2];
#pragma unroll
    for (int j = 0; j < 2; ++j) {
      e2x[j] = s2 ? e1x[2 * j + 1] : e1x[2 * j];
      e2y[j] = s2 ? e1y[2 * j + 1] : e1y[2 * j];
      e2z[j] = s2 ? e1z[2 * j + 1] : e1z[2 * j];
    }
    float bx = s3 ? e2x[1] : e2x[0];
    float by = s3 ? e2y[1] : e2y[0];
    float bz = s3 ? e2z[1] : e2z[0];

    // first lane holding the wave max == lowest candidate index
    u64 msk = __ballot(__float_as_int(bestv) == wmaxb);
    int flane = (int)__builtin_ctzll(msk);
    if (lane == flane) {
      int besti = t * PT + bq;   // this lane's own best == wave winner
      rkey[buf][w] = ((u64)(u32)wmaxb << 32) | (u32)(0xFFFFFFFFu - (u32)besti);
      rcoord[buf][w] = make_float4(bx, by, bz, 0.0f);
    }
    __syncthreads();

    u64 k0 = rkey[buf][0], k1 = rkey[buf][1];
    u64 k2 = rkey[buf][2], k3 = rkey[buf][3];
    float4 q0 = rcoord[buf][0], q1 = rcoord[buf][1];
    float4 q2 = rcoord[buf][2], q3 = rcoord[buf][3];
    bool g01 = k0 > k1;
    u64 ka2 = g01 ? k0 : k1;
    float ax2 = g01 ? q0.x : q1.x, ay2 = g01 ? q0.y : q1.y, az2 = g01 ? q0.z : q1.z;
    bool g23 = k2 > k3;
    u64 kb2 = g23 ? k2 : k3;
    float bx2 = g23 ? q2.x : q3.x, by2 = g23 ? q2.y : q3.y, bz2 = g23 ? q2.z : q3.z;
    bool gf = ka2 > kb2;
    u64 km = gf ? ka2 : kb2;
    lx = gf ? ax2 : bx2; ly = gf ? ay2 : by2; lz = gf ? az2 : bz2;
    int last = (int)(0xFFFFFFFFu - (u32)(km & 0xFFFFFFFFu));
    if (t == 0) idxs[(size_t)b * NN + it + 1] = last;
  }
}

// ------------- selection kernel: one block per batch -------------
__global__ __launch_bounds__(SEL_T) void select_kernel(const float* __restrict__ x,
                                                       const float* __restrict__ curv,
                                                       const int* __restrict__ idxs,
                                                       float* __restrict__ out) {
  const int b = blockIdx.x;
  const int t = threadIdx.x;
  __shared__ u64 ka[SS];     // sca keys: (~vbits, i)  -> ascending == desc by v
  __shared__ u64 kb[4096];   // scb keys: (vbits, i)   -> ascending, 1024 pads
  __shared__ float rmn[8], rmx[8];

  const float* cb = curv + (size_t)b * NN;
  const int* ib = idxs + (size_t)b * NN;

  float mn = __builtin_inff(), mx = -__builtin_inff();
  float cv[8];
#pragma unroll
  for (int q = 0; q < 8; ++q) {
    float v = cb[q * SEL_T + t];
    cv[q] = v;
    mn = fminf(mn, v);
    mx = fmaxf(mx, v);
  }
#pragma unroll
  for (int s = 1; s < 64; s <<= 1) {
    mn = fminf(mn, __shfl_xor(mn, s, 64));
    mx = fmaxf(mx, __shfl_xor(mx, s, 64));
  }
  if ((t & 63) == 0) { rmn[t >> 6] = mn; rmx[t >> 6] = mx; }
  __syncthreads();
  mn = rmn[0]; mx = rmx[0];
#pragma unroll
  for (int w = 1; w < 8; ++w) { mn = fminf(mn, rmn[w]); mx = fmaxf(mx, rmx[w]); }
  float denom = __fsub_rn(mx, mn);

#pragma unroll
  for (int q = 0; q < 8; ++q) {
    int i = q * SEL_T + t;
    float cn = __fdiv_rn(__fsub_rn(cv[q], mn), denom);
    int id = ib[i];
    // jnp.linspace(1,0,4096)[id] = 1 - id/4095 (true division; id=4095 -> 0)
    float sv = __fsub_rn(1.0f, __fdiv_rn((float)id, 4095.0f));
    float scv = __fmul_rn(sv, cn);   // sc >= 0 -> bits are order-monotone
    u32 vb = __float_as_uint(scv);
    if (i < SS)
      ka[i] = ((u64)(vb ^ 0xFFFFFFFFu) << 32) | (u32)i;
    else
      kb[i - SS] = ((u64)vb << 32) | (u32)(i - SS);
  }
  for (int i = NBB + t; i < 4096; i += SEL_T) kb[i] = ~0ULL;  // pads to the top
  __syncthreads();

  // bitonic sort ka ascending (n=1024, 512 pairs: one per thread)
  for (u32 k = 2; k <= SS; k <<= 1) {
    for (u32 j = k >> 1; j > 0; j >>= 1) {
      u32 p = (u32)t;
      u32 i = ((p & ~(j - 1)) << 1) | (p & (j - 1));
      u32 l = i | j;
      bool up = ((i & k) == 0);
      u64 a = ka[i], c = ka[l];
      if ((a > c) == up) { ka[i] = c; ka[l] = a; }
      __syncthreads();
    }
  }
  // bitonic sort kb ascending (n=4096, 2048 pairs: 4 per thread)
  for (u32 k = 2; k <= 4096; k <<= 1) {
    for (u32 j = k >> 1; j > 0; j >>= 1) {
#pragma unroll
      for (u32 p = (u32)t; p < 2048; p += SEL_T) {
        u32 i = ((p & ~(j - 1)) << 1) | (p & (j - 1));
        u32 l = i | j;
        bool up = ((i & k) == 0);
        u64 a = kb[i], c = kb[l];
        if ((a > c) == up) { kb[i] = c; kb[l] = a; }
      }
      __syncthreads();
    }
  }

  // final[j]: j<922 -> ba_idx[j]; else tb beats ba ? tb_idx[j] : ba_idx[j]
#pragma unroll
  for (int j0 = 0; j0 < SS; j0 += SEL_T) {
    int j = j0 + t;
    u64 A = ka[j];
    int baid = (int)(u32)(A & 0xFFFFFFFFu);
    u32 babits = ((u32)(A >> 32)) ^ 0xFFFFFFFFu;
    int fin = baid;
    if (j >= SS - EE) {
      u64 Bk = kb[2048 + j];           // largest-1024 of scb, ascending
      u32 tbbits = (u32)(Bk >> 32);
      if (tbbits > babits) fin = (int)(u32)(Bk & 0xFFFFFFFFu) + SS;
    }
    int pt = ib[fin];
    out[(size_t)b * SS + j] = (float)fin;
    const float* xp = x + ((size_t)b * NN + (size_t)pt) * 3;
    float* op = out + (size_t)BB * SS + ((size_t)b * SS + (size_t)j) * 3;
    op[0] = xp[0];
    op[1] = xp[1];
    op[2] = xp[2];
  }
}

extern "C" void kernel_launch(void* const* d_in, const int* in_sizes, int n_in,
                              void* d_out, int out_size, void* d_ws, size_t ws_size,
                              hipStream_t stream) {
  (void)in_sizes; (void)n_in; (void)out_size; (void)ws_size;
  const float* x = (const float*)d_in[0];
  const float* curv = (const float*)d_in[1];
  int* idxs = (int*)d_ws;             // B*N int32 = 128 KB scratch
  float* out = (float*)d_out;

  fps_kernel<<<BB, FT, 0, stream>>>(x, idxs);
  select_kernel<<<BB, SEL_T, 0, stream>>>(x, curv, idxs, out);
}

// Round 6
// 2237.607 us; speedup vs baseline: 2.4436x; 2.4436x over previous
//
#include <hip/hip_runtime.h>
#include <stdint.h>

// Forbid mul+add contraction: pk_fma would change rounding vs the reference's
// separate mul/add ops. Critical scalar math also uses explicit __f*_rn.
#pragma clang fp contract(off)

typedef unsigned long long u64;
typedef unsigned int u32;
typedef float v2f __attribute__((ext_vector_type(2)));

#define BB 8
#define NN 4096
#define SS 1024
#define EE 102      // int(0.1 * 1024)
#define NBB 3072    // N - S
#define FT 256      // fps threads (4 waves, 1 per SIMD)
#define PT 16       // points per thread (contiguous: thread t owns [16t,16t+16))
#define SEL_T 512

// DPP wave64 max-reduce step (bound_ctrl: OOB lanes read 0; values >= 0).
template <int CTRL>
__device__ __forceinline__ float maxdpp(float v) {
  int m = __builtin_amdgcn_update_dpp(0, __float_as_int(v), CTRL, 0xf, 0xf, true);
  return fmaxf(v, __int_as_float(m));
}

// ---------------- FPS kernel: one block per batch ----------------
// Exact replica of _fps_order: d = (dx*dx+dy*dy)+dz*dz (no FMA), mind=min,
// argmax with lowest-index-first ties. Data layout: SCALAR float arrays only
// (round-2 proven to stay in registers). Packed-f32 math via v2f SSA
// temporaries: per-half rounding == scalar rn, bitwise identical.
__global__ __launch_bounds__(FT) void fps_kernel(const float* __restrict__ x,
                                                 int* __restrict__ idxs) {
  const int b = blockIdx.x;
  const int t = threadIdx.x;
  const int w = t >> 6;
  const int lane = t & 63;
  const float* xb = x + (size_t)b * NN * 3;

  __shared__ float4 lxyz[NN];   // 64 KB coord mirror for winner broadcast
  __shared__ u64 rkey[2][4];    // per-wave candidate keys, double-buffered

  float px[PT], py[PT], pz[PT], mind[PT];

  // load 16 contiguous points = 12 float4 per thread (fully coalesced block)
  const float4* xb4 = (const float4*)xb;
  float4 f[12];
#pragma unroll
  for (int j = 0; j < 12; ++j) f[j] = xb4[t * 12 + j];
#pragma unroll
  for (int g = 0; g < 4; ++g) {
    float4 a = f[g * 3 + 0], c = f[g * 3 + 1], d = f[g * 3 + 2];
    px[g * 4 + 0] = a.x; py[g * 4 + 0] = a.y; pz[g * 4 + 0] = a.z;
    px[g * 4 + 1] = a.w; py[g * 4 + 1] = c.x; pz[g * 4 + 1] = c.y;
    px[g * 4 + 2] = c.z; py[g * 4 + 2] = c.w; pz[g * 4 + 2] = d.x;
    px[g * 4 + 3] = d.y; py[g * 4 + 3] = d.z; pz[g * 4 + 3] = d.w;
  }
#pragma unroll
  for (int q = 0; q < PT; ++q) {
    lxyz[t * PT + q] = make_float4(px[q], py[q], pz[q], 0.0f);
    mind[q] = __builtin_inff();
  }
  if (t == 0) idxs[(size_t)b * NN] = 0;
  __syncthreads();

  float4 lp = lxyz[0];
  for (int it = 0; it < NN - 1; ++it) {
    v2f lx2, ly2, lz2;
    lx2.x = lp.x; lx2.y = lp.x;
    ly2.x = lp.y; ly2.y = lp.y;
    lz2.x = lp.z; lz2.y = lp.z;

    float bestv = -1.0f;
    int bq = 0;
#pragma unroll
    for (int q = 0; q < 8; ++q) {
      // v2f SSA temps from constant-indexed scalar arrays: v_pk_* math,
      // per-half rn rounding, no contraction (pragma above).
      v2f X; X.x = px[2 * q]; X.y = px[2 * q + 1];
      v2f Y; Y.x = py[2 * q]; Y.y = py[2 * q + 1];
      v2f Z; Z.x = pz[2 * q]; Z.y = pz[2 * q + 1];
      v2f dx = X - lx2;
      v2f dy = Y - ly2;
      v2f dz = Z - lz2;
      v2f dd = (dx * dx + dy * dy) + dz * dz;
      float m0 = fminf(mind[2 * q], dd.x);
      float m1 = fminf(mind[2 * q + 1], dd.y);
      mind[2 * q] = m0;
      mind[2 * q + 1] = m1;
      // ascending q => ascending global index; strict '>' keeps lowest index
      if (m0 > bestv) { bestv = m0; bq = 2 * q; }
      if (m1 > bestv) { bestv = m1; bq = 2 * q + 1; }
    }
    int besti = t * PT + bq;

    // wave64 max via DPP (all VALU): result in lane 63
    float r = bestv;
    r = maxdpp<0x111>(r);   // row_shr:1
    r = maxdpp<0x112>(r);   // row_shr:2
    r = maxdpp<0x114>(r);   // row_shr:4
    r = maxdpp<0x118>(r);   // row_shr:8
    r = maxdpp<0x142>(r);   // row_bcast:15
    r = maxdpp<0x143>(r);   // row_bcast:31
    int wmaxb = __builtin_amdgcn_readlane(__float_as_int(r), 63);

    // lowest lane holding the max == lowest candidate index (contiguous layout)
    u64 msk = __ballot(__float_as_int(bestv) == wmaxb);
    int flane = __ffsll((long long)msk) - 1;
    int widx = __builtin_amdgcn_readlane(besti, flane);

    u64 key = ((u64)(u32)wmaxb << 32) | (u32)(0xFFFFFFFFu - (u32)widx);
    if (lane == 0) rkey[it & 1][w] = key;
    __syncthreads();

    u64 k0 = rkey[it & 1][0], k1 = rkey[it & 1][1];
    u64 k2 = rkey[it & 1][2], k3 = rkey[it & 1][3];
    u64 m01 = k0 > k1 ? k0 : k1;
    u64 m23 = k2 > k3 ? k2 : k3;
    u64 km = m01 > m23 ? m01 : m23;
    int last = (int)(0xFFFFFFFFu - (u32)(km & 0xFFFFFFFFu));
    if (t == 0) idxs[(size_t)b * NN + it + 1] = last;
    lp = lxyz[last];
  }
}

// ------------- selection kernel: one block per batch -------------
__global__ __launch_bounds__(SEL_T) void select_kernel(const float* __restrict__ x,
                                                       const float* __restrict__ curv,
                                                       const int* __restrict__ idxs,
                                                       float* __restrict__ out) {
  const int b = blockIdx.x;
  const int t = threadIdx.x;
  __shared__ u64 ka[SS];     // sca keys: (~vbits, i)  -> ascending == desc by v
  __shared__ u64 kb[4096];   // scb keys: (vbits, i)   -> ascending, 1024 pads
  __shared__ float rmn[8], rmx[8];

  const float* cb = curv + (size_t)b * NN;
  const int* ib = idxs + (size_t)b * NN;

  float mn = __builtin_inff(), mx = -__builtin_inff();
  float cv[8];
#pragma unroll
  for (int q = 0; q < 8; ++q) {
    float v = cb[q * SEL_T + t];
    cv[q] = v;
    mn = fminf(mn, v);
    mx = fmaxf(mx, v);
  }
#pragma unroll
  for (int s = 1; s < 64; s <<= 1) {
    mn = fminf(mn, __shfl_xor(mn, s, 64));
    mx = fmaxf(mx, __shfl_xor(mx, s, 64));
  }
  if ((t & 63) == 0) { rmn[t >> 6] = mn; rmx[t >> 6] = mx; }
  __syncthreads();
  mn = rmn[0]; mx = rmx[0];
#pragma unroll
  for (int w = 1; w < 8; ++w) { mn = fminf(mn, rmn[w]); mx = fmaxf(mx, rmx[w]); }
  float denom = __fsub_rn(mx, mn);

#pragma unroll
  for (int q = 0; q < 8; ++q) {
    int i = q * SEL_T + t;
    float cn = __fdiv_rn(__fsub_rn(cv[q], mn), denom);
    int id = ib[i];
    // jnp.linspace(1,0,4096)[id] = 1 - id/4095 (true division; id=4095 -> 0)
    float sv = __fsub_rn(1.0f, __fdiv_rn((float)id, 4095.0f));
    float scv = __fmul_rn(sv, cn);   // sc >= 0 -> bits are order-monotone
    u32 vb = __float_as_uint(scv);
    if (i < SS)
      ka[i] = ((u64)(vb ^ 0xFFFFFFFFu) << 32) | (u32)i;
    else
      kb[i - SS] = ((u64)vb << 32) | (u32)(i - SS);
  }
  for (int i = NBB + t; i < 4096; i += SEL_T) kb[i] = ~0ULL;  // pads to the top
  __syncthreads();

  // bitonic sort ka ascending (n=1024, 512 pairs: one per thread)
  for (u32 k = 2; k <= SS; k <<= 1) {
    for (u32 j = k >> 1; j > 0; j >>= 1) {
      u32 p = (u32)t;
      u32 i = ((p & ~(j - 1)) << 1) | (p & (j - 1));
      u32 l = i | j;
      bool up = ((i & k) == 0);
      u64 a = ka[i], c = ka[l];
      if ((a > c) == up) { ka[i] = c; ka[l] = a; }
      __syncthreads();
    }
  }
  // bitonic sort kb ascending (n=4096, 2048 pairs: 4 per thread)
  for (u32 k = 2; k <= 4096; k <<= 1) {
    for (u32 j = k >> 1; j > 0; j >>= 1) {
#pragma unroll
      for (u32 p = (u32)t; p < 2048; p += SEL_T) {
        u32 i = ((p & ~(j - 1)) << 1) | (p & (j - 1));
        u32 l = i | j;
        bool up = ((i & k) == 0);
        u64 a = kb[i], c = kb[l];
        if ((a > c) == up) { kb[i] = c; kb[l] = a; }
      }
      __syncthreads();
    }
  }

  // final[j]: j<922 -> ba_idx[j]; else tb beats ba ? tb_idx[j] : ba_idx[j]
#pragma unroll
  for (int j0 = 0; j0 < SS; j0 += SEL_T) {
    int j = j0 + t;
    u64 A = ka[j];
    int baid = (int)(u32)(A & 0xFFFFFFFFu);
    u32 babits = ((u32)(A >> 32)) ^ 0xFFFFFFFFu;
    int fin = baid;
    if (j >= SS - EE) {
      u64 Bk = kb[2048 + j];           // largest-1024 of scb, ascending
      u32 tbbits = (u32)(Bk >> 32);
      if (tbbits > babits) fin = (int)(u32)(Bk & 0xFFFFFFFFu) + SS;
    }
    int pt = ib[fin];
    out[(size_t)b * SS + j] = (float)fin;
    const float* xp = x + ((size_t)b * NN + (size_t)pt) * 3;
    float* op = out + (size_t)BB * SS + ((size_t)b * SS + (size_t)j) * 3;
    op[0] = xp[0];
    op[1] = xp[1];
    op[2] = xp[2];
  }
}

extern "C" void kernel_launch(void* const* d_in, const int* in_sizes, int n_in,
                              void* d_out, int out_size, void* d_ws, size_t ws_size,
                              hipStream_t stream) {
  (void)in_sizes; (void)n_in; (void)out_size; (void)ws_size;
  const float* x = (const float*)d_in[0];
  const float* curv = (const float*)d_in[1];
  int* idxs = (int*)d_ws;             // B*N int32 = 128 KB scratch
  float* out = (float*)d_out;

  fps_kernel<<<BB, FT, 0, stream>>>(x, idxs);
  select_kernel<<<BB, SEL_T, 0, stream>>>(x, curv, idxs, out);
}